// Round 7
// baseline (156.385 us; speedup 1.0000x reference)
//
#include <hip/hip_runtime.h>
#include <hip/hip_bf16.h>
#include <stdint.h>

#define HIDDEN 128

typedef __attribute__((ext_vector_type(8))) short bf16x8;
typedef __attribute__((ext_vector_type(16))) float f32x16;

// f32 pair -> packed bf16x2 (RNE) via HIP's pair conversion; the compiler
// lowers this to the hardware packed-cvt path on gfx950 (do NOT hand-write
// the bit-trick: ~5 VALU ops/elem vs 1 packed op per 2 elems).
static __device__ __forceinline__ uint32_t cvt2(float a, float b) {
    union { __hip_bfloat162 h2; uint32_t u; } c;
    c.h2 = __float22bfloat162_rn(make_float2(a, b));
    return c.u;
}
static __device__ __forceinline__ float bf_lo(uint32_t p) {
    union { uint32_t u; float f; } v; v.u = p << 16; return v.f;
}
static __device__ __forceinline__ float bf_hi(uint32_t p) {
    union { uint32_t u; float f; } v; v.u = p & 0xffff0000u; return v.f;
}
static __device__ __forceinline__ bf16x8 pack8(float4 a, float4 b) {
    union { uint32_t u[4]; bf16x8 v; } r;
    r.u[0] = cvt2(a.x, a.y); r.u[1] = cvt2(a.z, a.w);
    r.u[2] = cvt2(b.x, b.y); r.u[3] = cvt2(b.z, b.w);
    return r.v;
}

// ---------------- precompute: UV = z @ Bm (+b1 on u-half) ----------------
// mfma_f32_32x32x16_bf16, A = W-fragment (rows = cc), B = z-fragment
// (cols = node). Wave w owns cc in [w*64, w*64+64). W fragments in VGPRs.
// 2-deep z prefetch pipeline; accumulators staged to LDS (swizzled), then
// cooperatively copied out as full 512-B rows (full-line stores).

struct ZBuf { float4 a[8], b[8]; };  // raw fp32 z for one node-slice

static __device__ __forceinline__ void load_z(ZBuf& zb, const float* __restrict__ z,
                                              int ng, int nl, int hi, int n_nodes) {
    int node = ng * 32 + nl;
    node = (node < n_nodes) ? node : (n_nodes - 1);
    const float* zrow = z + (size_t)node * HIDDEN;
    #pragma unroll
    for (int ks = 0; ks < 8; ++ks) {
        zb.a[ks] = *reinterpret_cast<const float4*>(zrow + ks * 16 + hi * 8);
        zb.b[ks] = *reinterpret_cast<const float4*>(zrow + ks * 16 + hi * 8 + 4);
    }
}

// LDS tile: 32 nodes x 256 cols bf16 = 16 KB. Byte addr for (node, colb):
//   node*512 + (colb ^ ((node & 15) << 3))     (colb multiple of 8)
static __device__ __forceinline__ void compute_to_lds(
    const ZBuf& zb, const bf16x8 (&wf)[2][8], const f32x16 (&binit)[2],
    char* Sm, int nl, int hi, int w)
{
    bf16x8 zf[8];
    #pragma unroll
    for (int ks = 0; ks < 8; ++ks) zf[ks] = pack8(zb.a[ks], zb.b[ks]);

    f32x16 acc0 = binit[0];
    f32x16 acc1 = binit[1];
    #pragma unroll
    for (int ks = 0; ks < 8; ++ks) {
        acc0 = __builtin_amdgcn_mfma_f32_32x32x16_bf16(wf[0][ks], zf[ks], acc0, 0, 0, 0);
        acc1 = __builtin_amdgcn_mfma_f32_32x32x16_bf16(wf[1][ks], zf[ks], acc1, 0, 0, 0);
    }

    const int swz = (nl & 15) << 3;
    #pragma unroll
    for (int g = 0; g < 4; ++g) {
        uint2 s0, s1;
        s0.x = cvt2(acc0[4 * g + 0], acc0[4 * g + 1]);
        s0.y = cvt2(acc0[4 * g + 2], acc0[4 * g + 3]);
        s1.x = cvt2(acc1[4 * g + 0], acc1[4 * g + 1]);
        s1.y = cvt2(acc1[4 * g + 2], acc1[4 * g + 3]);
        const int colb0 = w * 128 + g * 16 + hi * 8;          // cg = 0
        const int colb1 = w * 128 + 64 + g * 16 + hi * 8;     // cg = 1
        *reinterpret_cast<uint2*>(Sm + nl * 512 + (colb0 ^ swz)) = s0;
        *reinterpret_cast<uint2*>(Sm + nl * 512 + (colb1 ^ swz)) = s1;
    }
}

static __device__ __forceinline__ void copy_out(
    unsigned short* __restrict__ UV, const char* Sm, int ng, int tid, int n_nodes)
{
    const int colb0 = (tid & 31) * 16;       // 16-B chunk within a 512-B row
    #pragma unroll
    for (int rep = 0; rep < 4; ++rep) {
        const int node_local = rep * 8 + (tid >> 5);
        const int swz = (node_local & 15) << 3;
        const uint2 g0 = *reinterpret_cast<const uint2*>(Sm + node_local * 512 + ((colb0) ^ swz));
        const uint2 g1 = *reinterpret_cast<const uint2*>(Sm + node_local * 512 + ((colb0 + 8) ^ swz));
        const int node = ng * 32 + node_local;
        if (node < n_nodes) {
            uint4 o = { g0.x, g0.y, g1.x, g1.y };
            *reinterpret_cast<uint4*>(UV + (size_t)node * 256 + (tid & 31) * 8) = o;
        }
    }
}

__global__ __launch_bounds__(256) void precompute_mfma32(
    const float* __restrict__ z, const float* __restrict__ W1,
    const float* __restrict__ b1,
    unsigned short* __restrict__ UV, int n_nodes, int n_groups)
{
    __shared__ char Sm[32 * 512];   // 16 KB output staging tile

    const int tid = threadIdx.x;
    const int lane = tid & 63;
    const int w = tid >> 6;
    const int nl = lane & 31;
    const int hi = lane >> 5;

    // ---- W fragments (A-operand), loaded once; coalesced across nl ----
    bf16x8 wf[2][8];
    #pragma unroll
    for (int cg = 0; cg < 2; ++cg) {
        const int cc = w * 64 + cg * 32 + nl;
        const int ccol = cc & 127;
        const int kofs = (cc >= 128) ? 128 : 0;
        #pragma unroll
        for (int ks = 0; ks < 8; ++ks) {
            const int k0 = ks * 16 + hi * 8 + kofs;
            float t[8];
            #pragma unroll
            for (int j = 0; j < 8; ++j)
                t[j] = W1[(size_t)(k0 + j) * 128 + ccol];
            union { uint32_t u[4]; bf16x8 v; } fu;
            fu.u[0] = cvt2(t[0], t[1]); fu.u[1] = cvt2(t[2], t[3]);
            fu.u[2] = cvt2(t[4], t[5]); fu.u[3] = cvt2(t[6], t[7]);
            wf[cg][ks] = fu.v;
        }
    }

    // ---- accumulator init = b1 (u-half) or 0 (v-half) ----
    f32x16 binit[2];
    #pragma unroll
    for (int cg = 0; cg < 2; ++cg) {
        const int cc0 = w * 64 + cg * 32;
        #pragma unroll
        for (int r = 0; r < 16; ++r) {
            const int crow = (r & 3) + 8 * (r >> 2) + 4 * hi;
            const int cc = cc0 + crow;
            binit[cg][r] = (cc < 128) ? b1[cc] : 0.f;
        }
    }

    const int stride = gridDim.x;
    int ng = blockIdx.x;
    if (ng >= n_groups) return;

    ZBuf bufA, bufB;
    load_z(bufA, z, ng, nl, hi, n_nodes);

    while (ng < n_groups) {
        const int n1 = ng + stride;
        if (n1 < n_groups) load_z(bufB, z, n1, nl, hi, n_nodes);
        compute_to_lds(bufA, wf, binit, Sm, nl, hi, w);
        __syncthreads();
        copy_out(UV, Sm, ng, tid, n_nodes);
        __syncthreads();
        if (n1 >= n_groups) break;

        const int n2 = n1 + stride;
        if (n2 < n_groups) load_z(bufA, z, n2, nl, hi, n_nodes);
        compute_to_lds(bufB, wf, binit, Sm, nl, hi, w);
        __syncthreads();
        copy_out(UV, Sm, n1, tid, n_nodes);
        __syncthreads();
        ng = n2;
    }
}

// ---------------- edge scoring ----------------
// score[e] = sum_j relu(u'[src][j] + v[dst][j]) * W2[j] + b2   (u' has b1)
// 16 lanes per edge, 8 edges per lane-group; all 16 gathers fenced ahead
// of compute (MSHR saturation; see round-6 analysis).
static __device__ __forceinline__ float dot8(uint4 u, uint4 v, const float* w) {
    const uint32_t up[4] = { u.x, u.y, u.z, u.w };
    const uint32_t vp[4] = { v.x, v.y, v.z, v.w };
    float s = 0.f;
    #pragma unroll
    for (int p = 0; p < 4; ++p) {
        const float h0 = bf_lo(up[p]) + bf_lo(vp[p]);
        const float h1 = bf_hi(up[p]) + bf_hi(vp[p]);
        s = fmaf(fmaxf(h0, 0.f), w[2 * p], s);
        s = fmaf(fmaxf(h1, 0.f), w[2 * p + 1], s);
    }
    return s;
}
static __device__ __forceinline__ float red16(float s) {
    s += __shfl_xor(s, 1, 64); s += __shfl_xor(s, 2, 64);
    s += __shfl_xor(s, 4, 64); s += __shfl_xor(s, 8, 64);
    return s;
}

#define EPG 8  // edges per 16-lane group

__global__ __launch_bounds__(256, 4) void edge_score(
    const int* __restrict__ ei, const unsigned short* __restrict__ UV,
    const float* __restrict__ W2, const float* __restrict__ b2,
    float* __restrict__ out, int n_edges)
{
    const int g = (blockIdx.x * 256 + threadIdx.x) >> 4;
    const int q = threadIdx.x & 15;
    const int e0 = g * EPG;
    if (e0 >= n_edges) return;

    const float4 w2a = *reinterpret_cast<const float4*>(W2 + q * 8);
    const float4 w2b = *reinterpret_cast<const float4*>(W2 + q * 8 + 4);
    const float wloc[8] = { w2a.x, w2a.y, w2a.z, w2a.w, w2b.x, w2b.y, w2b.z, w2b.w };
    const float bias = b2[0];

    const char* UVb = (const char*)UV;
    const uint32_t qo = (uint32_t)q * 16u;

    if (e0 + EPG - 1 < n_edges) {
        const int4 sA = *reinterpret_cast<const int4*>(ei + e0);
        const int4 sB = *reinterpret_cast<const int4*>(ei + e0 + 4);
        const int4 dA = *reinterpret_cast<const int4*>(ei + n_edges + e0);
        const int4 dB = *reinterpret_cast<const int4*>(ei + n_edges + e0 + 4);
        const int sidx[EPG] = { sA.x, sA.y, sA.z, sA.w, sB.x, sB.y, sB.z, sB.w };
        const int didx[EPG] = { dA.x, dA.y, dA.z, dA.w, dB.x, dB.y, dB.z, dB.w };

        uint4 u[EPG], v[EPG];
        #pragma unroll
        for (int i = 0; i < EPG; ++i) {
            u[i] = *reinterpret_cast<const uint4*>(UVb + ((uint32_t)sidx[i] * 512u + qo));
            v[i] = *reinterpret_cast<const uint4*>(UVb + ((uint32_t)didx[i] * 512u + 256u + qo));
        }
        // Fence: no compute may be hoisted above / loads sunk below.
        __builtin_amdgcn_sched_barrier(0);

        float s[EPG];
        #pragma unroll
        for (int i = 0; i < EPG; ++i) s[i] = dot8(u[i], v[i], wloc);
        #pragma unroll
        for (int i = 0; i < EPG; ++i) s[i] = red16(s[i]) + bias;

        if (q == 0) {
            float4 oA = { s[0], s[1], s[2], s[3] };
            float4 oB = { s[4], s[5], s[6], s[7] };
            *reinterpret_cast<float4*>(out + e0) = oA;
            *reinterpret_cast<float4*>(out + e0 + 4) = oB;
        }
    } else {
        for (int i = 0; i < EPG; ++i) {
            const int e = e0 + i;
            if (e >= n_edges) break;
            const int si = ei[e];
            const int di = ei[n_edges + e];
            const uint4 uu = *reinterpret_cast<const uint4*>(UVb + ((uint32_t)si * 512u + qo));
            const uint4 vv = *reinterpret_cast<const uint4*>(UVb + ((uint32_t)di * 512u + 256u + qo));
            float s = red16(dot8(uu, vv, wloc));
            if (q == 0) out[e] = s + bias;
        }
    }
}

extern "C" void kernel_launch(void* const* d_in, const int* in_sizes, int n_in,
                              void* d_out, int out_size, void* d_ws, size_t ws_size,
                              hipStream_t stream) {
    const float* z  = (const float*)d_in[0];
    const int*   ei = (const int*)d_in[1];
    const float* W1 = (const float*)d_in[2];
    const float* b1 = (const float*)d_in[3];
    const float* W2 = (const float*)d_in[4];
    const float* b2 = (const float*)d_in[5];
    float* out = (float*)d_out;

    const int n_nodes = in_sizes[0] / HIDDEN;
    const int n_edges = in_sizes[1] / 2;

    unsigned short* UV = (unsigned short*)d_ws;  // [n_nodes][256] bf16, b1 folded into u-half

    // Kernel 1: per-node u/v via register-resident-W 32x32x16 MFMA,
    // packed-cvt conversions, LDS-staged full-line stores, 2-deep pipeline
    {
        const int n_groups = (n_nodes + 31) / 32;
        const int g1 = n_groups < 1024 ? n_groups : 1024;  // 4 blocks/CU
        precompute_mfma32<<<g1, 256, 0, stream>>>(z, W1, b1, UV, n_nodes, n_groups);
    }
    // Kernel 2: per-edge score, 8 edges per 16-lane group, fenced-deep MLP
    {
        const int groups = (n_edges + EPG - 1) / EPG;
        const int blocks = (groups * 16 + 255) / 256;
        edge_score<<<blocks, 256, 0, stream>>>(ei, UV, W2, b2, out, n_edges);
    }
}

// Round 8
// 152.928 us; speedup vs baseline: 1.0226x; 1.0226x over previous
//
#include <hip/hip_runtime.h>
#include <hip/hip_bf16.h>
#include <stdint.h>

#define HIDDEN 128

typedef __attribute__((ext_vector_type(8))) short bf16x8;
typedef __attribute__((ext_vector_type(16))) float f32x16;

// f32 pair -> packed bf16x2 (RNE)
static __device__ __forceinline__ uint32_t cvt2(float a, float b) {
    union { __hip_bfloat162 h2; uint32_t u; } c;
    c.h2 = __float22bfloat162_rn(make_float2(a, b));
    return c.u;
}
static __device__ __forceinline__ float bf_lo(uint32_t p) {
    union { uint32_t u; float f; } v; v.u = p << 16; return v.f;
}
static __device__ __forceinline__ float bf_hi(uint32_t p) {
    union { uint32_t u; float f; } v; v.u = p & 0xffff0000u; return v.f;
}
static __device__ __forceinline__ bf16x8 pack8(float4 a, float4 b) {
    union { uint32_t u[4]; bf16x8 v; } r;
    r.u[0] = cvt2(a.x, a.y); r.u[1] = cvt2(a.z, a.w);
    r.u[2] = cvt2(b.x, b.y); r.u[3] = cvt2(b.z, b.w);
    return r.v;
}

// ---------------- kernel 0: W1 -> Wt (transposed bf16) ----------------
// Wt[cc][k] = bf16(W1[k + 128*(cc>=128)][cc & 127]),  [256][128] row-major.
// One-time 64 KB; makes precompute's W-fragment loads single bf16x8 loads.
__global__ __launch_bounds__(256) void transpose_w1(
    const float* __restrict__ W1, unsigned short* __restrict__ Wt)
{
    const int t = blockIdx.x * 256 + threadIdx.x;   // 4096 total
    if (t >= 4096) return;
    const int cc = t >> 4;          // 0..255
    const int kg = t & 15;          // 0..15 (8 k's each)
    const int ccol = cc & 127;
    const int kofs = (cc >= 128) ? 128 : 0;
    uint32_t u[4];
    #pragma unroll
    for (int p = 0; p < 4; ++p) {
        const float a = W1[(size_t)(kofs + kg * 8 + 2 * p) * 128 + ccol];
        const float b = W1[(size_t)(kofs + kg * 8 + 2 * p + 1) * 128 + ccol];
        u[p] = cvt2(a, b);
    }
    uint4 o = { u[0], u[1], u[2], u[3] };
    *reinterpret_cast<uint4*>(Wt + (size_t)cc * 128 + kg * 8) = o;  // coalesced
}

// ---------------- precompute: UV = z @ Bm (+b1 on u-half) ----------------
// mfma_f32_32x32x16_bf16, A = W-fragment (rows = cc), B = z-fragment
// (cols = node). Wave w owns cc in [w*64, w*64+64). W fragments in VGPRs
// (loaded from Wt as single bf16x8 vector loads; scalar W1 fallback).
// 2-deep z prefetch pipeline; accumulators staged to LDS (swizzled), then
// cooperatively copied out as full 512-B rows (full-line stores).

struct ZBuf { float4 a[8], b[8]; };  // raw fp32 z for one node-slice

static __device__ __forceinline__ void load_z(ZBuf& zb, const float* __restrict__ z,
                                              int ng, int nl, int hi, int n_nodes) {
    int node = ng * 32 + nl;
    node = (node < n_nodes) ? node : (n_nodes - 1);
    const float* zrow = z + (size_t)node * HIDDEN;
    #pragma unroll
    for (int ks = 0; ks < 8; ++ks) {
        zb.a[ks] = *reinterpret_cast<const float4*>(zrow + ks * 16 + hi * 8);
        zb.b[ks] = *reinterpret_cast<const float4*>(zrow + ks * 16 + hi * 8 + 4);
    }
}

// LDS tile: 32 nodes x 256 cols bf16 = 16 KB. Byte addr for (node, colb):
//   node*512 + (colb ^ ((node & 15) << 3))     (colb multiple of 8)
static __device__ __forceinline__ void compute_to_lds(
    const ZBuf& zb, const bf16x8 (&wf)[2][8], const f32x16 (&binit)[2],
    char* Sm, int nl, int hi, int w)
{
    bf16x8 zf[8];
    #pragma unroll
    for (int ks = 0; ks < 8; ++ks) zf[ks] = pack8(zb.a[ks], zb.b[ks]);

    f32x16 acc0 = binit[0];
    f32x16 acc1 = binit[1];
    #pragma unroll
    for (int ks = 0; ks < 8; ++ks) {
        acc0 = __builtin_amdgcn_mfma_f32_32x32x16_bf16(wf[0][ks], zf[ks], acc0, 0, 0, 0);
        acc1 = __builtin_amdgcn_mfma_f32_32x32x16_bf16(wf[1][ks], zf[ks], acc1, 0, 0, 0);
    }

    const int swz = (nl & 15) << 3;
    #pragma unroll
    for (int g = 0; g < 4; ++g) {
        uint2 s0, s1;
        s0.x = cvt2(acc0[4 * g + 0], acc0[4 * g + 1]);
        s0.y = cvt2(acc0[4 * g + 2], acc0[4 * g + 3]);
        s1.x = cvt2(acc1[4 * g + 0], acc1[4 * g + 1]);
        s1.y = cvt2(acc1[4 * g + 2], acc1[4 * g + 3]);
        const int colb0 = w * 128 + g * 16 + hi * 8;          // cg = 0
        const int colb1 = w * 128 + 64 + g * 16 + hi * 8;     // cg = 1
        *reinterpret_cast<uint2*>(Sm + nl * 512 + (colb0 ^ swz)) = s0;
        *reinterpret_cast<uint2*>(Sm + nl * 512 + (colb1 ^ swz)) = s1;
    }
}

static __device__ __forceinline__ void copy_out(
    unsigned short* __restrict__ UV, const char* Sm, int ng, int tid, int n_nodes)
{
    const int colb0 = (tid & 31) * 16;       // 16-B chunk within a 512-B row
    #pragma unroll
    for (int rep = 0; rep < 4; ++rep) {
        const int node_local = rep * 8 + (tid >> 5);
        const int swz = (node_local & 15) << 3;
        const uint2 g0 = *reinterpret_cast<const uint2*>(Sm + node_local * 512 + ((colb0) ^ swz));
        const uint2 g1 = *reinterpret_cast<const uint2*>(Sm + node_local * 512 + ((colb0 + 8) ^ swz));
        const int node = ng * 32 + node_local;
        if (node < n_nodes) {
            uint4 o = { g0.x, g0.y, g1.x, g1.y };
            *reinterpret_cast<uint4*>(UV + (size_t)node * 256 + (tid & 31) * 8) = o;
        }
    }
}

__global__ __launch_bounds__(256) void precompute_mfma32(
    const float* __restrict__ z, const float* __restrict__ W1,
    const unsigned short* __restrict__ Wt,   // may be null -> fallback
    const float* __restrict__ b1,
    unsigned short* __restrict__ UV, int n_nodes, int n_groups)
{
    __shared__ char Sm[32 * 512];   // 16 KB output staging tile

    const int tid = threadIdx.x;
    const int lane = tid & 63;
    const int w = tid >> 6;
    const int nl = lane & 31;
    const int hi = lane >> 5;

    // ---- W fragments (A-operand), loaded once ----
    bf16x8 wf[2][8];
    if (Wt) {
        #pragma unroll
        for (int cg = 0; cg < 2; ++cg) {
            const int cc = w * 64 + cg * 32 + nl;
            #pragma unroll
            for (int ks = 0; ks < 8; ++ks) {
                const int k0 = ks * 16 + hi * 8;
                wf[cg][ks] = *reinterpret_cast<const bf16x8*>(Wt + (size_t)cc * 128 + k0);
            }
        }
    } else {
        #pragma unroll
        for (int cg = 0; cg < 2; ++cg) {
            const int cc = w * 64 + cg * 32 + nl;
            const int ccol = cc & 127;
            const int kofs = (cc >= 128) ? 128 : 0;
            #pragma unroll
            for (int ks = 0; ks < 8; ++ks) {
                const int k0 = ks * 16 + hi * 8 + kofs;
                float t[8];
                #pragma unroll
                for (int j = 0; j < 8; ++j)
                    t[j] = W1[(size_t)(k0 + j) * 128 + ccol];
                union { uint32_t u[4]; bf16x8 v; } fu;
                fu.u[0] = cvt2(t[0], t[1]); fu.u[1] = cvt2(t[2], t[3]);
                fu.u[2] = cvt2(t[4], t[5]); fu.u[3] = cvt2(t[6], t[7]);
                wf[cg][ks] = fu.v;
            }
        }
    }

    // ---- accumulator init = b1 (u-half) or 0 (v-half) ----
    f32x16 binit[2];
    #pragma unroll
    for (int cg = 0; cg < 2; ++cg) {
        const int cc0 = w * 64 + cg * 32;
        #pragma unroll
        for (int r = 0; r < 16; ++r) {
            const int crow = (r & 3) + 8 * (r >> 2) + 4 * hi;
            const int cc = cc0 + crow;
            binit[cg][r] = (cc < 128) ? b1[cc] : 0.f;
        }
    }

    const int stride = gridDim.x;
    int ng = blockIdx.x;
    if (ng >= n_groups) return;

    ZBuf bufA, bufB;
    load_z(bufA, z, ng, nl, hi, n_nodes);

    while (ng < n_groups) {
        const int n1 = ng + stride;
        if (n1 < n_groups) load_z(bufB, z, n1, nl, hi, n_nodes);
        compute_to_lds(bufA, wf, binit, Sm, nl, hi, w);
        __syncthreads();
        copy_out(UV, Sm, ng, tid, n_nodes);
        __syncthreads();
        if (n1 >= n_groups) break;

        const int n2 = n1 + stride;
        if (n2 < n_groups) load_z(bufA, z, n2, nl, hi, n_nodes);
        compute_to_lds(bufB, wf, binit, Sm, nl, hi, w);
        __syncthreads();
        copy_out(UV, Sm, n1, tid, n_nodes);
        __syncthreads();
        ng = n2;
    }
}

// ---------------- edge scoring ----------------
// score[e] = sum_j relu(u'[src][j] + v[dst][j]) * W2[j] + b2   (u' has b1)
// 16 lanes per edge, 8 edges per lane-group; all 16 gathers fenced ahead
// of compute (TCC-miss-path throughput bound; see round-6/7 analysis).
static __device__ __forceinline__ float dot8(uint4 u, uint4 v, const float* w) {
    const uint32_t up[4] = { u.x, u.y, u.z, u.w };
    const uint32_t vp[4] = { v.x, v.y, v.z, v.w };
    float s = 0.f;
    #pragma unroll
    for (int p = 0; p < 4; ++p) {
        const float h0 = bf_lo(up[p]) + bf_lo(vp[p]);
        const float h1 = bf_hi(up[p]) + bf_hi(vp[p]);
        s = fmaf(fmaxf(h0, 0.f), w[2 * p], s);
        s = fmaf(fmaxf(h1, 0.f), w[2 * p + 1], s);
    }
    return s;
}
static __device__ __forceinline__ float red16(float s) {
    s += __shfl_xor(s, 1, 64); s += __shfl_xor(s, 2, 64);
    s += __shfl_xor(s, 4, 64); s += __shfl_xor(s, 8, 64);
    return s;
}

#define EPG 8  // edges per 16-lane group

__global__ __launch_bounds__(256, 4) void edge_score(
    const int* __restrict__ ei, const unsigned short* __restrict__ UV,
    const float* __restrict__ W2, const float* __restrict__ b2,
    float* __restrict__ out, int n_edges)
{
    const int g = (blockIdx.x * 256 + threadIdx.x) >> 4;
    const int q = threadIdx.x & 15;
    const int e0 = g * EPG;
    if (e0 >= n_edges) return;

    const float4 w2a = *reinterpret_cast<const float4*>(W2 + q * 8);
    const float4 w2b = *reinterpret_cast<const float4*>(W2 + q * 8 + 4);
    const float wloc[8] = { w2a.x, w2a.y, w2a.z, w2a.w, w2b.x, w2b.y, w2b.z, w2b.w };
    const float bias = b2[0];

    const char* UVb = (const char*)UV;
    const uint32_t qo = (uint32_t)q * 16u;

    if (e0 + EPG - 1 < n_edges) {
        const int4 sA = *reinterpret_cast<const int4*>(ei + e0);
        const int4 sB = *reinterpret_cast<const int4*>(ei + e0 + 4);
        const int4 dA = *reinterpret_cast<const int4*>(ei + n_edges + e0);
        const int4 dB = *reinterpret_cast<const int4*>(ei + n_edges + e0 + 4);
        const int sidx[EPG] = { sA.x, sA.y, sA.z, sA.w, sB.x, sB.y, sB.z, sB.w };
        const int didx[EPG] = { dA.x, dA.y, dA.z, dA.w, dB.x, dB.y, dB.z, dB.w };

        uint4 u[EPG], v[EPG];
        #pragma unroll
        for (int i = 0; i < EPG; ++i) {
            u[i] = *reinterpret_cast<const uint4*>(UVb + ((uint32_t)sidx[i] * 512u + qo));
            v[i] = *reinterpret_cast<const uint4*>(UVb + ((uint32_t)didx[i] * 512u + 256u + qo));
        }
        // Fence: no compute may be hoisted above / loads sunk below.
        __builtin_amdgcn_sched_barrier(0);

        float s[EPG];
        #pragma unroll
        for (int i = 0; i < EPG; ++i) s[i] = dot8(u[i], v[i], wloc);
        #pragma unroll
        for (int i = 0; i < EPG; ++i) s[i] = red16(s[i]) + bias;

        if (q == 0) {
            float4 oA = { s[0], s[1], s[2], s[3] };
            float4 oB = { s[4], s[5], s[6], s[7] };
            *reinterpret_cast<float4*>(out + e0) = oA;
            *reinterpret_cast<float4*>(out + e0 + 4) = oB;
        }
    } else {
        for (int i = 0; i < EPG; ++i) {
            const int e = e0 + i;
            if (e >= n_edges) break;
            const int si = ei[e];
            const int di = ei[n_edges + e];
            const uint4 uu = *reinterpret_cast<const uint4*>(UVb + ((uint32_t)si * 512u + qo));
            const uint4 vv = *reinterpret_cast<const uint4*>(UVb + ((uint32_t)di * 512u + 256u + qo));
            float s = red16(dot8(uu, vv, wloc));
            if (q == 0) out[e] = s + bias;
        }
    }
}

extern "C" void kernel_launch(void* const* d_in, const int* in_sizes, int n_in,
                              void* d_out, int out_size, void* d_ws, size_t ws_size,
                              hipStream_t stream) {
    const float* z  = (const float*)d_in[0];
    const int*   ei = (const int*)d_in[1];
    const float* W1 = (const float*)d_in[2];
    const float* b1 = (const float*)d_in[3];
    const float* W2 = (const float*)d_in[4];
    const float* b2 = (const float*)d_in[5];
    float* out = (float*)d_out;

    const int n_nodes = in_sizes[0] / HIDDEN;
    const int n_edges = in_sizes[1] / 2;

    unsigned short* UV = (unsigned short*)d_ws;  // [n_nodes][256] bf16, b1 folded into u-half
    const size_t uv_bytes = (size_t)n_nodes * 256 * sizeof(unsigned short);

    // Wt (transposed bf16 W1, 64 KB) lives after UV in d_ws if it fits.
    unsigned short* Wt = nullptr;
    if (ws_size >= uv_bytes + 256 * 128 * sizeof(unsigned short))
        Wt = UV + (size_t)n_nodes * 256;

    // Kernel 0: one-time W1 transpose+convert (16 blocks)
    if (Wt) transpose_w1<<<16, 256, 0, stream>>>(W1, Wt);

    // Kernel 1: per-node u/v via register-resident-W 32x32x16 MFMA,
    // LDS-staged full-line stores, 2-deep z prefetch pipeline
    {
        const int n_groups = (n_nodes + 31) / 32;
        const int g1 = n_groups < 512 ? n_groups : 512;  // 2 blocks/CU
        precompute_mfma32<<<g1, 256, 0, stream>>>(z, W1, Wt, b1, UV, n_nodes, n_groups);
    }
    // Kernel 2: per-edge score, 8 edges per 16-lane group, fenced-deep MLP
    {
        const int groups = (n_edges + EPG - 1) / EPG;
        const int blocks = (groups * 16 + 255) / 256;
        edge_score<<<blocks, 256, 0, stream>>>(ei, UV, W2, b2, out, n_edges);
    }
}

// Round 9
// 133.775 us; speedup vs baseline: 1.1690x; 1.1432x over previous
//
#include <hip/hip_runtime.h>
#include <hip/hip_bf16.h>
#include <stdint.h>

#define HIDDEN 128

typedef __attribute__((ext_vector_type(8))) short bf16x8;
typedef __attribute__((ext_vector_type(16))) float f32x16;

// f32 pair -> packed bf16x2 (RNE)
static __device__ __forceinline__ uint32_t cvt2(float a, float b) {
    union { __hip_bfloat162 h2; uint32_t u; } c;
    c.h2 = __float22bfloat162_rn(make_float2(a, b));
    return c.u;
}
static __device__ __forceinline__ float bf_lo(uint32_t p) {
    union { uint32_t u; float f; } v; v.u = p << 16; return v.f;
}
static __device__ __forceinline__ float bf_hi(uint32_t p) {
    union { uint32_t u; float f; } v; v.u = p & 0xffff0000u; return v.f;
}

// ---------------- kernel 0: W1 -> Wt (transposed bf16) ----------------
// Wt[cc][k] = bf16(W1[k + 128*(cc>=128)][cc & 127]),  [256][128] row-major.
__global__ __launch_bounds__(256) void transpose_w1(
    const float* __restrict__ W1, unsigned short* __restrict__ Wt)
{
    const int t = blockIdx.x * 256 + threadIdx.x;   // 4096 total
    if (t >= 4096) return;
    const int cc = t >> 4;          // 0..255
    const int kg = t & 15;          // 0..15 (8 k's each)
    const int ccol = cc & 127;
    const int kofs = (cc >= 128) ? 128 : 0;
    uint32_t u[4];
    #pragma unroll
    for (int p = 0; p < 4; ++p) {
        const float a = W1[(size_t)(kofs + kg * 8 + 2 * p) * 128 + ccol];
        const float b = W1[(size_t)(kofs + kg * 8 + 2 * p + 1) * 128 + ccol];
        u[p] = cvt2(a, b);
    }
    uint4 o = { u[0], u[1], u[2], u[3] };
    *reinterpret_cast<uint4*>(Wt + (size_t)cc * 128 + kg * 8) = o;
}

// ---------------- precompute: UV = z @ Bm  (no bias; b1 in edge kernel) ----
// mfma_f32_32x32x16_bf16, A = W-fragment (rows = cc), B = z-fragment
// (cols = node). Wave w owns cc in [w*64, w*64+64). W fragments in VGPRs.
// z staged ONCE per block per 32-node group into an 8 KB bf16 LDS tile
// (XOR-swizzled), read back as MFMA fragments by all 4 waves.
// Output staged to a 16 KB LDS tile, copied out as full 512-B rows.

// ztile byte addr for (node_local, 16B-chunk m):  node*256 + ((m*16) ^ ((node&7)<<4))
// outtile byte addr for (node_local, 8B colb):    node*512 + (colb ^ ((node&15)<<3))

__global__ __launch_bounds__(256) void precompute_mfma32(
    const float* __restrict__ z, const float* __restrict__ W1,
    const unsigned short* __restrict__ Wt,   // may be null -> scalar fallback
    unsigned short* __restrict__ UV, int n_nodes, int n_groups)
{
    __shared__ char Zt[32 * 256];   //  8 KB bf16 z tile
    __shared__ char Sm[32 * 512];   // 16 KB output staging tile

    const int tid = threadIdx.x;
    const int lane = tid & 63;
    const int w = tid >> 6;
    const int nl = lane & 31;
    const int hi = lane >> 5;

    // stage role: thread t covers node_local = t>>3, k = (t&7)*16 .. +15
    const int st_node = tid >> 3;
    const int st_j2 = tid & 7;
    const int st_swz = (st_node & 7) << 4;
    const int st_addrA = st_node * 256 + ((st_j2 * 32) ^ st_swz);
    const int st_addrB = st_node * 256 + ((st_j2 * 32 + 16) ^ st_swz);

    // ---- W fragments (A-operand), loaded once ----
    bf16x8 wf[2][8];
    if (Wt) {
        #pragma unroll
        for (int cg = 0; cg < 2; ++cg) {
            const int cc = w * 64 + cg * 32 + nl;
            #pragma unroll
            for (int ks = 0; ks < 8; ++ks)
                wf[cg][ks] = *reinterpret_cast<const bf16x8*>(
                    Wt + (size_t)cc * 128 + ks * 16 + hi * 8);
        }
    } else {
        #pragma unroll
        for (int cg = 0; cg < 2; ++cg) {
            const int cc = w * 64 + cg * 32 + nl;
            const int ccol = cc & 127;
            const int kofs = (cc >= 128) ? 128 : 0;
            #pragma unroll
            for (int ks = 0; ks < 8; ++ks) {
                const int k0 = ks * 16 + hi * 8 + kofs;
                float t[8];
                #pragma unroll
                for (int j = 0; j < 8; ++j)
                    t[j] = W1[(size_t)(k0 + j) * 128 + ccol];
                union { uint32_t u[4]; bf16x8 v; } fu;
                fu.u[0] = cvt2(t[0], t[1]); fu.u[1] = cvt2(t[2], t[3]);
                fu.u[2] = cvt2(t[4], t[5]); fu.u[3] = cvt2(t[6], t[7]);
                wf[cg][ks] = fu.v;
            }
        }
    }

    const int stride = gridDim.x;
    int ng = blockIdx.x;
    if (ng >= n_groups) return;

    // prologue: load first group's z slice (64 B/thread) into registers
    float4 nz0, nz1, nz2, nz3;
    {
        int node = ng * 32 + st_node;
        node = (node < n_nodes) ? node : (n_nodes - 1);
        const float* zp = z + (size_t)node * HIDDEN + st_j2 * 16;
        nz0 = *reinterpret_cast<const float4*>(zp);
        nz1 = *reinterpret_cast<const float4*>(zp + 4);
        nz2 = *reinterpret_cast<const float4*>(zp + 8);
        nz3 = *reinterpret_cast<const float4*>(zp + 12);
    }

    while (ng < n_groups) {
        // 1) ds_write this group's z (from regs), swizzled bf16
        {
            uint4 A, B;
            A.x = cvt2(nz0.x, nz0.y); A.y = cvt2(nz0.z, nz0.w);
            A.z = cvt2(nz1.x, nz1.y); A.w = cvt2(nz1.z, nz1.w);
            B.x = cvt2(nz2.x, nz2.y); B.y = cvt2(nz2.z, nz2.w);
            B.z = cvt2(nz3.x, nz3.y); B.w = cvt2(nz3.z, nz3.w);
            *reinterpret_cast<uint4*>(Zt + st_addrA) = A;
            *reinterpret_cast<uint4*>(Zt + st_addrB) = B;
        }

        // 2) issue next group's z loads into regs (overlaps compute below)
        const int ngn = ng + stride;
        if (ngn < n_groups) {
            int node = ngn * 32 + st_node;
            node = (node < n_nodes) ? node : (n_nodes - 1);
            const float* zp = z + (size_t)node * HIDDEN + st_j2 * 16;
            nz0 = *reinterpret_cast<const float4*>(zp);
            nz1 = *reinterpret_cast<const float4*>(zp + 4);
            nz2 = *reinterpret_cast<const float4*>(zp + 8);
            nz3 = *reinterpret_cast<const float4*>(zp + 12);
        }

        __syncthreads();   // ztile ready (and previous copy_out done)

        // 3) MFMA from ztile; epilogue -> out tile
        {
            const int rd_swz = (nl & 7) << 4;
            bf16x8 zf[8];
            #pragma unroll
            for (int ks = 0; ks < 8; ++ks) {
                const int off = ks * 32 + hi * 16;
                zf[ks] = *reinterpret_cast<const bf16x8*>(
                    Zt + nl * 256 + (off ^ rd_swz));
            }

            f32x16 acc0 = {};
            f32x16 acc1 = {};
            #pragma unroll
            for (int ks = 0; ks < 8; ++ks) {
                acc0 = __builtin_amdgcn_mfma_f32_32x32x16_bf16(wf[0][ks], zf[ks], acc0, 0, 0, 0);
                acc1 = __builtin_amdgcn_mfma_f32_32x32x16_bf16(wf[1][ks], zf[ks], acc1, 0, 0, 0);
            }

            const int swz = (nl & 15) << 3;
            #pragma unroll
            for (int g = 0; g < 4; ++g) {
                uint2 s0, s1;
                s0.x = cvt2(acc0[4 * g + 0], acc0[4 * g + 1]);
                s0.y = cvt2(acc0[4 * g + 2], acc0[4 * g + 3]);
                s1.x = cvt2(acc1[4 * g + 0], acc1[4 * g + 1]);
                s1.y = cvt2(acc1[4 * g + 2], acc1[4 * g + 3]);
                const int colb0 = w * 128 + g * 16 + hi * 8;
                const int colb1 = w * 128 + 64 + g * 16 + hi * 8;
                *reinterpret_cast<uint2*>(Sm + nl * 512 + (colb0 ^ swz)) = s0;
                *reinterpret_cast<uint2*>(Sm + nl * 512 + (colb1 ^ swz)) = s1;
            }
        }

        __syncthreads();   // out tile ready; ztile free next iter

        // 4) copy out full 512-B rows
        {
            const int colb0 = (tid & 31) * 16;
            #pragma unroll
            for (int rep = 0; rep < 4; ++rep) {
                const int node_local = rep * 8 + (tid >> 5);
                const int swz = (node_local & 15) << 3;
                const uint2 g0 = *reinterpret_cast<const uint2*>(Sm + node_local * 512 + ((colb0) ^ swz));
                const uint2 g1 = *reinterpret_cast<const uint2*>(Sm + node_local * 512 + ((colb0 + 8) ^ swz));
                const int node = ng * 32 + node_local;
                if (node < n_nodes) {
                    uint4 o = { g0.x, g0.y, g1.x, g1.y };
                    *reinterpret_cast<uint4*>(UV + (size_t)node * 256 + (tid & 31) * 8) = o;
                }
            }
        }

        ng = ngn;
    }
}

// ---------------- edge scoring ----------------
// score[e] = sum_j relu(u[src][j] + v[dst][j] + b1[j]) * W2[j] + b2
// 16 lanes per edge, 8 edges per lane-group; gathers fenced ahead of
// compute (TCC-miss-path throughput bound; rounds 4-8 analysis).
static __device__ __forceinline__ float dot8(uint4 u, uint4 v,
                                             const float* w, const float* bb) {
    const uint32_t up[4] = { u.x, u.y, u.z, u.w };
    const uint32_t vp[4] = { v.x, v.y, v.z, v.w };
    float s = 0.f;
    #pragma unroll
    for (int p = 0; p < 4; ++p) {
        const float h0 = bf_lo(up[p]) + bf_lo(vp[p]) + bb[2 * p];
        const float h1 = bf_hi(up[p]) + bf_hi(vp[p]) + bb[2 * p + 1];
        s = fmaf(fmaxf(h0, 0.f), w[2 * p], s);
        s = fmaf(fmaxf(h1, 0.f), w[2 * p + 1], s);
    }
    return s;
}
static __device__ __forceinline__ float red16(float s) {
    s += __shfl_xor(s, 1, 64); s += __shfl_xor(s, 2, 64);
    s += __shfl_xor(s, 4, 64); s += __shfl_xor(s, 8, 64);
    return s;
}

#define EPG 8  // edges per 16-lane group

__global__ __launch_bounds__(256, 4) void edge_score(
    const int* __restrict__ ei, const unsigned short* __restrict__ UV,
    const float* __restrict__ b1, const float* __restrict__ W2,
    const float* __restrict__ b2, float* __restrict__ out, int n_edges)
{
    const int g = (blockIdx.x * 256 + threadIdx.x) >> 4;
    const int q = threadIdx.x & 15;
    const int e0 = g * EPG;
    if (e0 >= n_edges) return;

    const float4 w2a = *reinterpret_cast<const float4*>(W2 + q * 8);
    const float4 w2b = *reinterpret_cast<const float4*>(W2 + q * 8 + 4);
    const float wloc[8] = { w2a.x, w2a.y, w2a.z, w2a.w, w2b.x, w2b.y, w2b.z, w2b.w };
    const float4 b1a = *reinterpret_cast<const float4*>(b1 + q * 8);
    const float4 b1b = *reinterpret_cast<const float4*>(b1 + q * 8 + 4);
    const float bb[8] = { b1a.x, b1a.y, b1a.z, b1a.w, b1b.x, b1b.y, b1b.z, b1b.w };
    const float bias = b2[0];

    const char* UVb = (const char*)UV;
    const uint32_t qo = (uint32_t)q * 16u;

    if (e0 + EPG - 1 < n_edges) {
        const int4 sA = *reinterpret_cast<const int4*>(ei + e0);
        const int4 sB = *reinterpret_cast<const int4*>(ei + e0 + 4);
        const int4 dA = *reinterpret_cast<const int4*>(ei + n_edges + e0);
        const int4 dB = *reinterpret_cast<const int4*>(ei + n_edges + e0 + 4);
        const int sidx[EPG] = { sA.x, sA.y, sA.z, sA.w, sB.x, sB.y, sB.z, sB.w };
        const int didx[EPG] = { dA.x, dA.y, dA.z, dA.w, dB.x, dB.y, dB.z, dB.w };

        uint4 u[EPG], v[EPG];
        #pragma unroll
        for (int i = 0; i < EPG; ++i) {
            u[i] = *reinterpret_cast<const uint4*>(UVb + ((uint32_t)sidx[i] * 512u + qo));
            v[i] = *reinterpret_cast<const uint4*>(UVb + ((uint32_t)didx[i] * 512u + 256u + qo));
        }
        __builtin_amdgcn_sched_barrier(0);

        float s[EPG];
        #pragma unroll
        for (int i = 0; i < EPG; ++i) s[i] = dot8(u[i], v[i], wloc, bb);
        #pragma unroll
        for (int i = 0; i < EPG; ++i) s[i] = red16(s[i]) + bias;

        if (q == 0) {
            float4 oA = { s[0], s[1], s[2], s[3] };
            float4 oB = { s[4], s[5], s[6], s[7] };
            *reinterpret_cast<float4*>(out + e0) = oA;
            *reinterpret_cast<float4*>(out + e0 + 4) = oB;
        }
    } else {
        for (int i = 0; i < EPG; ++i) {
            const int e = e0 + i;
            if (e >= n_edges) break;
            const int si = ei[e];
            const int di = ei[n_edges + e];
            const uint4 uu = *reinterpret_cast<const uint4*>(UVb + ((uint32_t)si * 512u + qo));
            const uint4 vv = *reinterpret_cast<const uint4*>(UVb + ((uint32_t)di * 512u + 256u + qo));
            float s = red16(dot8(uu, vv, wloc, bb));
            if (q == 0) out[e] = s + bias;
        }
    }
}

extern "C" void kernel_launch(void* const* d_in, const int* in_sizes, int n_in,
                              void* d_out, int out_size, void* d_ws, size_t ws_size,
                              hipStream_t stream) {
    const float* z  = (const float*)d_in[0];
    const int*   ei = (const int*)d_in[1];
    const float* W1 = (const float*)d_in[2];
    const float* b1 = (const float*)d_in[3];
    const float* W2 = (const float*)d_in[4];
    const float* b2 = (const float*)d_in[5];
    float* out = (float*)d_out;

    const int n_nodes = in_sizes[0] / HIDDEN;
    const int n_edges = in_sizes[1] / 2;

    unsigned short* UV = (unsigned short*)d_ws;  // [n_nodes][256] bf16 (u|v), no bias folded
    const size_t uv_bytes = (size_t)n_nodes * 256 * sizeof(unsigned short);

    unsigned short* Wt = nullptr;
    if (ws_size >= uv_bytes + 256 * 128 * sizeof(unsigned short))
        Wt = UV + (size_t)n_nodes * 256;

    if (Wt) transpose_w1<<<16, 256, 0, stream>>>(W1, Wt);

    // Kernel 1: shared bf16 z-tile in LDS, register-resident W fragments,
    // LDS out-staging with full-line stores
    {
        const int n_groups = (n_nodes + 31) / 32;
        const int g1 = n_groups < 768 ? n_groups : 768;
        precompute_mfma32<<<g1, 256, 0, stream>>>(z, W1, Wt, UV, n_nodes, n_groups);
    }
    // Kernel 2: per-edge score, 8 edges per 16-lane group, fenced-deep MLP
    {
        const int groups = (n_edges + EPG - 1) / EPG;
        const int blocks = (groups * 16 + 255) / 256;
        edge_score<<<blocks, 256, 0, stream>>>(ei, UV, b1, W2, b2, out, n_edges);
    }
}